// Round 1
// baseline (71.656 us; speedup 1.0000x reference)
//
#include <hip/hip_runtime.h>

// ConvCNP encoder: out[b,c,jy,ix] = FM[b, g=ix*128+jy, c]
//   density = sum_n exp(-0.5*||grid_g - X_bn||^2); ch1,2 = weighted Y / density
// B=4, N_CTX=1024, grid = meshgrid('ij') of linspace(-2,2,128).
//
// R2: separable Gaussian, 4x4 tile/thread, 32 N-chunks  -> 68.3 us.
// R3 (this): issue-roofline says ~6 us; gap => latency-bound at 2 waves/SIMD.
//   - NQ 32->64 (CHUNK=16), TPB 8->4, 1024 blocks -> 4 blocks/CU = 4 waves/SIMD.
//   - LDS aliased: staging (17.4KB, dead after main loop) UNION reduction
//     (26.6KB) so 4 blocks/CU fit (4 x 26.6 = 106KB <= 160KB).
//   - __launch_bounds__(256,4) caps VGPR <= 128 for the 16-wave/CU target.

#define N_CTX   1024
#define G_PER_B 16384
#define NQ      64            // N-chunks
#define CHUNK   (N_CTX / NQ)  // 16
#define TPB     4             // tiles per block (256 thr = 4 tiles x 64 chunks)
#define SSTRIDE (CHUNK + 1)   // 17: +16B pad per chunk -> 2-way bank alias max

typedef float fv4 __attribute__((ext_vector_type(4)));

__device__ __forceinline__ float fast_exp2(float x) {
#if __has_builtin(__builtin_amdgcn_exp2f)
  return __builtin_amdgcn_exp2f(x);
#else
  return exp2f(x);
#endif
}

#define RED_BYTES (32 * TPB * 13 * 16)  // 26624 B: tree buffer [32][TPB][13] fv4
#define S_BYTES   ((N_CTX + NQ) * 16)   // 17408 B: staging (1088 float4)

__global__ __launch_bounds__(256, 4) void convcnp_encoder_kernel(
    const float* __restrict__ X,     // [B, N_CTX, 2]
    const float* __restrict__ Y,     // [B, N_CTX, 2]
    const float* __restrict__ grid,  // [G_PER_B, 2]
    float* __restrict__ out)         // [B, 3, 128, 128]
{
  // staging and reduction alias the same LDS region (staging dead after loop)
  __shared__ __attribute__((aligned(16))) unsigned char smem[RED_BYTES];
  float4* s = (float4*)smem;                       // [1088] w/ pad every 16
  fv4 (*red)[TPB][13] = (fv4 (*)[TPB][13])smem;    // 13 (not 12): bank spread

  const int t    = threadIdx.x;
  const int tile = t & (TPB - 1);  // tile slot in block
  const int q    = t >> 2;         // N-chunk index, 0..63

  const int tau = blockIdx.x * TPB + tile;  // global tile id, 0..4095
  const int b   = tau >> 10;                // uniform per block (1024 % 4 == 0)
  const int rem = tau & 1023;
  const int ixt = rem & 31;                 // tile's ix group (4 ix each)
  const int jyt = rem >> 5;                 // tile's jy group (uniform per block)

  // SC = sqrt(0.5*log2(e)): w = exp2(-(dx')^2) * exp2(-(dy')^2)
  const float SC = 0.84932180028801907f;

  // ---- stage this batch's context points into LDS (coalesced) ----
  const float2* Xb = (const float2*)(X + b * (N_CTX * 2));
  const float2* Yb = (const float2*)(Y + b * (N_CTX * 2));
#pragma unroll
  for (int k = 0; k < 4; ++k) {
    int n = t + 256 * k;
    float2 x = Xb[n];
    float2 y = Yb[n];
    s[n + (n >> 4)] = make_float4(x.x * SC, x.y * SC, y.x, y.y);
  }

  // ---- per-thread grid coords (one-time scattered loads, L2-cached) ----
  fv4 gxs;
#pragma unroll
  for (int a = 0; a < 4; ++a)
    gxs[a] = grid[(4 * ixt + a) * 256] * SC;     // gx[ix] = grid[2*(ix*128)]
  float gys[4];
#pragma unroll
  for (int bb = 0; bb < 4; ++bb)
    gys[bb] = grid[2 * (4 * jyt + bb) + 1] * SC; // gy[jy] = grid[2*jy+1]

  __syncthreads();

  fv4 acc0[4], acc1[4], acc2[4];   // [jy-sub], components = ix-sub
#pragma unroll
  for (int bb = 0; bb < 4; ++bb) {
    acc0[bb] = (fv4){0.f, 0.f, 0.f, 0.f};
    acc1[bb] = (fv4){0.f, 0.f, 0.f, 0.f};
    acc2[bb] = (fv4){0.f, 0.f, 0.f, 0.f};
  }

  // ---- main loop: 16 ctx points for this chunk ----
  const float4* sp = &s[q * SSTRIDE];
#pragma unroll 4
  for (int it = 0; it < CHUNK; ++it) {
    float4 v = sp[it];             // (x0*SC, x1*SC, y0, y1)
    fv4 dx = gxs - v.x;
    fv4 ex;
#pragma unroll
    for (int a = 0; a < 4; ++a) ex[a] = fast_exp2(-(dx[a] * dx[a]));
    float ey[4], ey0[4], ey1[4];
#pragma unroll
    for (int bb = 0; bb < 4; ++bb) {
      float dy = gys[bb] - v.y;
      float e  = fast_exp2(-(dy * dy));
      ey[bb]  = e;
      ey0[bb] = e * v.z;
      ey1[bb] = e * v.w;
    }
#pragma unroll
    for (int bb = 0; bb < 4; ++bb) {
      acc0[bb] += ex * ey[bb];     // 4 fma each (vector * splat + add)
      acc1[bb] += ex * ey0[bb];
      acc2[bb] += ex * ey1[bb];
    }
  }

  // staging region is dead from here; reduction buffer aliases it.
  __syncthreads();

  // ---- 6-level cross-chunk tree reduction (64 -> 1) in LDS ----
#pragma unroll
  for (int step = 32; step >= 1; step >>= 1) {
    if (q >= step && q < 2 * step) {
      fv4* d = &red[q - step][tile][0];
#pragma unroll
      for (int bb = 0; bb < 4; ++bb) {
        d[bb] = acc0[bb]; d[4 + bb] = acc1[bb]; d[8 + bb] = acc2[bb];
      }
    }
    __syncthreads();
    if (q < step) {
      fv4* r = &red[q][tile][0];
#pragma unroll
      for (int bb = 0; bb < 4; ++bb) {
        acc0[bb] += r[bb]; acc1[bb] += r[4 + bb]; acc2[bb] += r[8 + bb];
      }
    }
    __syncthreads();
  }

  // ---- epilogue: q==0 threads hold final sums for their tile ----
  if (q == 0) {
    const int ob = b * (3 * G_PER_B) + jyt * 4 * 128 + ixt * 4;
#pragma unroll
    for (int bb = 0; bb < 4; ++bb) {
      fv4 d  = acc0[bb];
      fv4 o1 = acc1[bb] / d;
      fv4 o2 = acc2[bb] / d;
      const int row = ob + bb * 128;
      *(fv4*)(out + row)                = d;   // 16B aligned: ixt*4 floats
      *(fv4*)(out + row + G_PER_B)      = o1;
      *(fv4*)(out + row + 2 * G_PER_B)  = o2;
    }
  }
}

extern "C" void kernel_launch(void* const* d_in, const int* in_sizes, int n_in,
                              void* d_out, int out_size, void* d_ws, size_t ws_size,
                              hipStream_t stream) {
  const float* X    = (const float*)d_in[0];
  const float* Y    = (const float*)d_in[1];
  const float* grid = (const float*)d_in[2];
  float* out        = (float*)d_out;

  // 4096 tiles / 4 per block = 1024 blocks (4/CU = 16 waves/CU), 256 threads.
  convcnp_encoder_kernel<<<dim3(1024), dim3(256), 0, stream>>>(X, Y, grid, out);
}